// Round 2
// 459.467 us; speedup vs baseline: 1.0500x; 1.0500x over previous
//
#include <hip/hip_runtime.h>

// MLPPredictor, round 8 (resubmit; round-1 bench was an infra failure —
// container acquire died twice, no dispatch ran).
// Exploit linearity of the edge GEMM:
//   score[e] = h[src]·W1^T + h[dst]·W2^T + eh[e]·W3^T + b
// r3-r7 all hit the scattered-gather wall (512 B of gathered h per edge,
// 16 lines per gather instr, ~135 cy/instr). Fix: precompute per-node
// partials P1[n]=h[n]·W1^T+b, P2[n]=h[n]·W2^T (N x 10 f32, padded to one
// 64 B line per row, 6.4 MB each -> L2/L3-resident). Per-edge gather is
// now 2 x 40 B inside aligned 64 B lines (4 lines/instr, was 16), and h
// is read ONCE, coalesced, in prep. Main kernel keeps only the eh·W3^T
// MFMA (4 MFMAs/tile) over the irreducible 307 MB eh stream.

typedef __attribute__((ext_vector_type(8))) short short8;
typedef __attribute__((ext_vector_type(4))) float f32x4;

#define NC    10
#define TPW   4            // 16-edge tiles per wave
#define NFRAG 12           // K=384 / 32 (full W frags; main uses t=8..11)
#define FRAG_BYTES 12288   // 12*64*16
#define PSTRIDE 16         // floats per P-table row (64 B, one line)

__device__ __forceinline__ unsigned short f2bf(float f) {
    unsigned u = __builtin_bit_cast(unsigned, f);
    u += 0x7FFFu + ((u >> 16) & 1u);          // round-to-nearest-even
    return (unsigned short)(u >> 16);
}

__device__ __forceinline__ short8 cvt8(f32x4 a, f32x4 b) {
    short8 s;
    s[0]=(short)f2bf(a[0]); s[1]=(short)f2bf(a[1]);
    s[2]=(short)f2bf(a[2]); s[3]=(short)f2bf(a[3]);
    s[4]=(short)f2bf(b[0]); s[5]=(short)f2bf(b[1]);
    s[6]=(short)f2bf(b[2]); s[7]=(short)f2bf(b[3]);
    return s;
}

// ---- prep 1: B-fragments frag[t*64 + lane] from Ww (1 block, once) ----
// frag t covers k = t*32 + q*8 + j; t=0..3 -> W1 (h_u), 4..7 -> W2 (h_v),
// 8..11 -> W3 (eh). Cols n>=NC are zeroed.
__global__ void build_wfrag(const float* __restrict__ Ww, short8* __restrict__ frag) {
    const int l = threadIdx.x;
    const int n = l & 15;
    const int q = l >> 4;
#pragma unroll
    for (int t = 0; t < NFRAG; ++t) {
        short8 b = (short8)0;
        if (n < NC) {
            const float* w = Ww + n * 384 + t * 32 + q * 8;
            b = cvt8(*(const f32x4*)w, *(const f32x4*)(w + 4));
        }
        frag[t * 64 + l] = b;
    }
}

#define LGF(v0,v1,v2,v3,v4,v5,v6,v7,p)          \
    v0 = *(const f32x4*)((p) + 0);              \
    v1 = *(const f32x4*)((p) + 4);              \
    v2 = *(const f32x4*)((p) + 32);             \
    v3 = *(const f32x4*)((p) + 36);             \
    v4 = *(const f32x4*)((p) + 64);             \
    v5 = *(const f32x4*)((p) + 68);             \
    v6 = *(const f32x4*)((p) + 96);             \
    v7 = *(const f32x4*)((p) + 100);

// ---- prep 2: per-node partials. 16 nodes per wave, coalesced h reads. ----
// P1[n][c] = h[n]·W1^T[c] + b[c];  P2[n][c] = h[n]·W2^T[c].
// Cols c>=NC write exact 0 (zeroed B frags, zero bias) -> rows are clean
// 64 B units; the gather side never reads those columns anyway.
__global__ __launch_bounds__(64) void build_ptab(
    const float* __restrict__ h, const short8* __restrict__ frag,
    const float* __restrict__ Wb, float* __restrict__ P1,
    float* __restrict__ P2, int N)
{
    const int l = threadIdx.x;
    const int n = l & 15;
    const int q = l >> 4;
    short8 bf[8];
#pragma unroll
    for (int t = 0; t < 8; ++t) bf[t] = frag[t * 64 + l];
    const float bias = (n < NC) ? Wb[n] : 0.f;

    const long base = (long)blockIdx.x * 16;
    const long node = base + n;
    const long ndc = (node < N) ? node : (long)(N - 1);
    const float* ph = h + ndc * 128 + q * 8;

    f32x4 x0,x1,x2,x3,x4,x5,x6,x7;
    LGF(x0,x1,x2,x3,x4,x5,x6,x7, ph)
    const short8 a0 = cvt8(x0,x1), a1 = cvt8(x2,x3);
    const short8 a2 = cvt8(x4,x5), a3 = cvt8(x6,x7);

    f32x4 acc1 = {0.f,0.f,0.f,0.f}, acc2 = {0.f,0.f,0.f,0.f};
    acc1 = __builtin_amdgcn_mfma_f32_16x16x32_bf16(a0, bf[0], acc1, 0,0,0);
    acc1 = __builtin_amdgcn_mfma_f32_16x16x32_bf16(a1, bf[1], acc1, 0,0,0);
    acc1 = __builtin_amdgcn_mfma_f32_16x16x32_bf16(a2, bf[2], acc1, 0,0,0);
    acc1 = __builtin_amdgcn_mfma_f32_16x16x32_bf16(a3, bf[3], acc1, 0,0,0);
    acc2 = __builtin_amdgcn_mfma_f32_16x16x32_bf16(a0, bf[4], acc2, 0,0,0);
    acc2 = __builtin_amdgcn_mfma_f32_16x16x32_bf16(a1, bf[5], acc2, 0,0,0);
    acc2 = __builtin_amdgcn_mfma_f32_16x16x32_bf16(a2, bf[6], acc2, 0,0,0);
    acc2 = __builtin_amdgcn_mfma_f32_16x16x32_bf16(a3, bf[7], acc2, 0,0,0);

    // C/D: col = n (class), row(node-in-tile) = q*4 + r
#pragma unroll
    for (int r = 0; r < 4; ++r) {
        const long nd = base + q * 4 + r;
        if (nd < N) {
            P1[nd * PSTRIDE + n] = acc1[r] + bias;
            P2[nd * PSTRIDE + n] = acc2[r];
        }
    }
}

// ---- main: out[e] = eh[e]·W3^T (MFMA) + P1[src[e]] + P2[dst[e]] ----
__global__ __launch_bounds__(64, 4) void mlp_edge_fused(
    const float* __restrict__ eh,            // [E,128] f32 stream
    const short8* __restrict__ frag,         // prebuilt B-fragments
    const float* __restrict__ P1,            // [N,PSTRIDE]
    const float* __restrict__ P2,            // [N,PSTRIDE]
    const int*   __restrict__ src,
    const int*   __restrict__ dst,
    float* __restrict__ out,                 // [E,10]
    int E)
{
    const int l = threadIdx.x;        // 0..63
    const int n = l & 15;             // A-row (edge-in-tile) AND B-col (class)
    const int q = l >> 4;             // k-quad

    const short8 bf0 = frag[ 8 * 64 + l];
    const short8 bf1 = frag[ 9 * 64 + l];
    const short8 bf2 = frag[10 * 64 + l];
    const short8 bf3 = frag[11 * 64 + l];
    const int cn = (n < NC) ? n : 0;

    const long tile0 = (long)blockIdx.x * TPW;

#pragma unroll 1
    for (int tt = 0; tt < TPW; ++tt) {
        const long base = (tile0 + tt) * 16;
        if (base >= E) break;                       // uniform
        const long e  = base + n;
        const long ec = (e < E) ? e : (long)(E - 1);
        const float* pe = eh + ec * 128 + q * 8;

        // issue the long-latency eh stream first
        f32x4 z0,z1,z2,z3,z4,z5,z6,z7;
        LGF(z0,z1,z2,z3,z4,z5,z6,z7, pe)

        // epilogue operands: this lane's 4 output edges are base + q*4 + r.
        // src/dst (broadcast within q-group) then 40 B P-row gathers, all
        // in flight while the MFMAs wait on eh.
        int s2[4], d2[4];
#pragma unroll
        for (int r = 0; r < 4; ++r) {
            const long e2  = base + q * 4 + r;
            const long e2c = (e2 < E) ? e2 : (long)(E - 1);
            s2[r] = src[e2c];
            d2[r] = dst[e2c];
        }
        float pv1[4], pv2[4];
#pragma unroll
        for (int r = 0; r < 4; ++r) {
            pv1[r] = P1[(long)s2[r] * PSTRIDE + cn];
            pv2[r] = P2[(long)d2[r] * PSTRIDE + cn];
        }

        f32x4 acc = {0.f, 0.f, 0.f, 0.f};
        acc = __builtin_amdgcn_mfma_f32_16x16x32_bf16(cvt8(z0,z1), bf0, acc, 0,0,0);
        acc = __builtin_amdgcn_mfma_f32_16x16x32_bf16(cvt8(z2,z3), bf1, acc, 0,0,0);
        acc = __builtin_amdgcn_mfma_f32_16x16x32_bf16(cvt8(z4,z5), bf2, acc, 0,0,0);
        acc = __builtin_amdgcn_mfma_f32_16x16x32_bf16(cvt8(z6,z7), bf3, acc, 0,0,0);

        // C/D: col = n (class), row(edge-in-tile) = q*4 + r
        if (n < NC) {
#pragma unroll
            for (int r = 0; r < 4; ++r) {
                const long e2 = base + q * 4 + r;
                if (e2 < E) out[e2 * NC + n] = acc[r] + pv1[r] + pv2[r];
            }
        }
    }
}

// ---- fallback (ws too small): full-K f32-gather kernel (r7 behavior) ----
__global__ __launch_bounds__(64, 3) void mlp_edge_f32(
    const float* __restrict__ h, const float* __restrict__ eh,
    const short8* __restrict__ frag, const float* __restrict__ Wb,
    const int* __restrict__ src, const int* __restrict__ dst,
    float* __restrict__ out, int E)
{
    const int l = threadIdx.x;
    const int n = l & 15;
    const int q = l >> 4;

    short8 bf[NFRAG];
#pragma unroll
    for (int t = 0; t < NFRAG; ++t) bf[t] = frag[t * 64 + l];
    const float bias = (n < NC) ? Wb[n] : 0.f;

    const long tile0 = (long)blockIdx.x * TPW;

#pragma unroll 1
    for (int tt = 0; tt < TPW; ++tt) {
        const long base = (tile0 + tt) * 16;
        if (base >= E) break;
        const long e  = base + n;
        const long ec = (e < E) ? e : (long)(E - 1);
        const int  sA = src[ec];
        const int  dA = dst[ec];
        const float* pe = eh + ec * 128 + q * 8;
        const float* ps = h + (long)sA * 128 + q * 8;
        const float* pd = h + (long)dA * 128 + q * 8;

        f32x4 x0,x1,x2,x3,x4,x5,x6,x7;
        f32x4 y0,y1,y2,y3,y4,y5,y6,y7;
        f32x4 z0,z1,z2,z3,z4,z5,z6,z7;
        LGF(x0,x1,x2,x3,x4,x5,x6,x7, ps)
        LGF(y0,y1,y2,y3,y4,y5,y6,y7, pd)
        LGF(z0,z1,z2,z3,z4,z5,z6,z7, pe)

        f32x4 acc = {0.f, 0.f, 0.f, 0.f};
        acc = __builtin_amdgcn_mfma_f32_16x16x32_bf16(cvt8(x0,x1), bf[0], acc, 0,0,0);
        acc = __builtin_amdgcn_mfma_f32_16x16x32_bf16(cvt8(x2,x3), bf[1], acc, 0,0,0);
        acc = __builtin_amdgcn_mfma_f32_16x16x32_bf16(cvt8(x4,x5), bf[2], acc, 0,0,0);
        acc = __builtin_amdgcn_mfma_f32_16x16x32_bf16(cvt8(x6,x7), bf[3], acc, 0,0,0);
        acc = __builtin_amdgcn_mfma_f32_16x16x32_bf16(cvt8(y0,y1), bf[4], acc, 0,0,0);
        acc = __builtin_amdgcn_mfma_f32_16x16x32_bf16(cvt8(y2,y3), bf[5], acc, 0,0,0);
        acc = __builtin_amdgcn_mfma_f32_16x16x32_bf16(cvt8(y4,y5), bf[6], acc, 0,0,0);
        acc = __builtin_amdgcn_mfma_f32_16x16x32_bf16(cvt8(y6,y7), bf[7], acc, 0,0,0);
        acc = __builtin_amdgcn_mfma_f32_16x16x32_bf16(cvt8(z0,z1), bf[8],  acc, 0,0,0);
        acc = __builtin_amdgcn_mfma_f32_16x16x32_bf16(cvt8(z2,z3), bf[9],  acc, 0,0,0);
        acc = __builtin_amdgcn_mfma_f32_16x16x32_bf16(cvt8(z4,z5), bf[10], acc, 0,0,0);
        acc = __builtin_amdgcn_mfma_f32_16x16x32_bf16(cvt8(z6,z7), bf[11], acc, 0,0,0);

        if (n < NC) {
#pragma unroll
            for (int r = 0; r < 4; ++r) {
                const long e2 = base + q * 4 + r;
                if (e2 < E) out[e2 * NC + n] = acc[r] + bias;
            }
        }
    }
}

extern "C" void kernel_launch(void* const* d_in, const int* in_sizes, int n_in,
                              void* d_out, int out_size, void* d_ws, size_t ws_size,
                              hipStream_t stream) {
    const float* h   = (const float*)d_in[0];
    const float* eh  = (const float*)d_in[1];
    const float* Ww  = (const float*)d_in[2];
    const float* Wb  = (const float*)d_in[3];
    const int*   src = (const int*)d_in[4];
    const int*   dst = (const int*)d_in[5];
    float* out = (float*)d_out;

    const int E    = in_sizes[4];
    const int N128 = in_sizes[0];                  // N * 128 elements of h
    const int N    = N128 / 128;

    short8* frag = (short8*)d_ws;
    build_wfrag<<<1, 64, 0, stream>>>(Ww, frag);

    const int edgesPerBlock = 16 * TPW;            // 64
    const int blocks = (E + edgesPerBlock - 1) / edgesPerBlock;  // 9375

    const size_t pfloats = (size_t)N * PSTRIDE;    // per table
    const size_t need = (size_t)FRAG_BYTES + 2 * pfloats * sizeof(float);
    if (ws_size >= need) {
        float* P1 = (float*)((char*)d_ws + FRAG_BYTES);
        float* P2 = P1 + pfloats;
        build_ptab<<<(N + 15) / 16, 64, 0, stream>>>(h, frag, Wb, P1, P2, N);
        mlp_edge_fused<<<blocks, 64, 0, stream>>>(eh, frag, P1, P2, src, dst, out, E);
    } else {
        mlp_edge_f32<<<blocks, 64, 0, stream>>>(h, eh, frag, Wb, src, dst, out, E);
    }
}